// Round 10
// baseline (717.628 us; speedup 1.0000x reference)
//
#include <hip/hip_runtime.h>

#define DD 64
#define SCAN_T 1024
#define FCH 16   // output-feature chunk per accumulator block

// ---------- CSR build ----------

// histogram + per-edge rank within its dst (rank = atomic return value)
__global__ __launch_bounds__(256)
void hist_kernel(const int* __restrict__ dst, int* __restrict__ degi,
                 int* __restrict__ rank, int nE)
{
    for (int e = blockIdx.x * blockDim.x + threadIdx.x; e < nE;
         e += gridDim.x * blockDim.x) {
        int r = atomicAdd(&degi[dst[e]], 1);
        rank[e] = r;
    }
}

__global__ __launch_bounds__(SCAN_T)
void scan1_kernel(const int* __restrict__ degi, int* __restrict__ rs,
                  int* __restrict__ partials, int nN)
{
    __shared__ int s[SCAN_T];
    int tid = threadIdx.x;
    int gid = blockIdx.x * SCAN_T + tid;
    int v = (gid < nN) ? degi[gid] : 0;
    s[tid] = v;
    __syncthreads();
    for (int off = 1; off < SCAN_T; off <<= 1) {
        int t = (tid >= off) ? s[tid - off] : 0;
        __syncthreads();
        s[tid] += t;
        __syncthreads();
    }
    if (gid < nN) rs[gid] = s[tid] - v;   // exclusive
    if (tid == SCAN_T - 1) partials[blockIdx.x] = s[SCAN_T - 1];
}

// wave-parallel exclusive scan over <=128 block partials
__global__ void scan2_kernel(int* __restrict__ partials, int* __restrict__ rs,
                             int nblk, int nN)
{
    int lane = threadIdx.x;   // 64 threads
    int p0 = (lane < nblk) ? partials[lane] : 0;
    int p1 = (64 + lane < nblk) ? partials[64 + lane] : 0;
    int v0 = p0;
    for (int off = 1; off < 64; off <<= 1) {
        int t = __shfl_up(v0, off);
        if (lane >= off) v0 += t;
    }
    int total0 = __shfl(v0, 63);
    int v1 = p1;
    for (int off = 1; off < 64; off <<= 1) {
        int t = __shfl_up(v1, off);
        if (lane >= off) v1 += t;
    }
    int grand = total0 + __shfl(v1, 63);
    if (lane < nblk) partials[lane] = v0 - p0;
    if (64 + lane < nblk) partials[64 + lane] = total0 + v1 - p1;
    if (lane == 0) rs[nN] = grand;   // == nE
}

__global__ __launch_bounds__(SCAN_T)
void scan3_kernel(int* __restrict__ rs, const int* __restrict__ partials, int nN)
{
    int gid = blockIdx.x * SCAN_T + threadIdx.x;
    if (gid < nN) rs[gid] += partials[blockIdx.x];
}

// scatter src into CSR slot rs[d]+rank[e] — NO atomics
__global__ __launch_bounds__(256)
void fill_kernel(const int* __restrict__ src, const int* __restrict__ dst,
                 const int* __restrict__ rs, const int* __restrict__ rank,
                 int* __restrict__ csr, int nE)
{
    for (int e = blockIdx.x * blockDim.x + threadIdx.x; e < nE;
         e += gridDim.x * blockDim.x) {
        csr[rs[dst[e]] + rank[e]] = src[e];
    }
}

// ---------- weight precompute: collapse the two layers ----------
// M1 = W2l*W1l ; M2 = W2l*W1r + W2r*W1l ; M3 = W2r*W1r
// c1 = b1 @ W2l.T ; c0 = b1 @ W2r.T + b2
// out = agg2@M1.T + agg1@M2.T + x@M3.T + ind*c1 + c0
__global__ void prep_kernel(const float* __restrict__ W1l,
                            const float* __restrict__ W1r,
                            const float* __restrict__ W2l,
                            const float* __restrict__ W2r,
                            const float* __restrict__ b1,
                            const float* __restrict__ b2,
                            float* __restrict__ M1, float* __restrict__ M2,
                            float* __restrict__ M3, float* __restrict__ c0,
                            float* __restrict__ c1)
{
    int f = blockIdx.x;      // 64 blocks
    int k = threadIdx.x;     // 64 threads
    float m1 = 0.f, m2 = 0.f, m3 = 0.f;
    for (int j = 0; j < DD; ++j) {
        float a2l = W2l[f * DD + j];
        float a2r = W2r[f * DD + j];
        float w1l = W1l[j * DD + k];
        float w1r = W1r[j * DD + k];
        m1 = fmaf(a2l, w1l, m1);
        m2 = fmaf(a2l, w1r, m2);
        m2 = fmaf(a2r, w1l, m2);
        m3 = fmaf(a2r, w1r, m3);
    }
    M1[f * DD + k] = m1;
    M2[f * DD + k] = m2;
    M3[f * DD + k] = m3;
    float t1 = W2l[f * DD + k] * b1[k];
    float t0 = W2r[f * DD + k] * b1[k];
    for (int off = 1; off < 64; off <<= 1) {
        t1 += __shfl_xor(t1, off);
        t0 += __shfl_xor(t0, off);
    }
    if (k == 0) {
        c1[f] = t1;
        c0[f] = t0 + b2[f];
    }
}

// ---------- aggregation: mean over neighbors ----------
// Wave per node. 16-lane group g handles neighbor rows {j+g, j+4+g, j+8+g,
// j+12+g} with float4 loads -> 4 independent gathers in flight per step.
__global__ __launch_bounds__(256)
void aggregate_kernel(const float* __restrict__ xin,
                      const int* __restrict__ csr,
                      const int* __restrict__ rs,
                      float* __restrict__ aggr, int nN)
{
    int lane = threadIdx.x & 63;
    int w = threadIdx.x >> 6;
    int g  = lane >> 4;        // group 0..3
    int gl = lane & 15;        // lane within group
    int totWaves = gridDim.x * 4;
    for (int node = blockIdx.x * 4 + w; node < nN; node += totWaves) {
        int beg = rs[node], end = rs[node + 1];
        int deg = end - beg;
        float ax0 = 0.f, ay0 = 0.f, az0 = 0.f, aw0 = 0.f;
        float ax1 = 0.f, ay1 = 0.f, az1 = 0.f, aw1 = 0.f;
        float ax2 = 0.f, ay2 = 0.f, az2 = 0.f, aw2 = 0.f;
        float ax3 = 0.f, ay3 = 0.f, az3 = 0.f, aw3 = 0.f;
        for (int base = beg; base < end; base += 64) {
            int n = end - base;
            if (n > 64) n = 64;
            int myIdx = (lane < n) ? csr[base + lane] : 0;
            for (int j = 0; j < n; j += 16) {
                int i0 = j + g;
                int i1 = j + 4 + g;
                int i2 = j + 8 + g;
                int i3 = j + 12 + g;
                int s0 = __shfl(myIdx, i0 & 63);
                int s1 = __shfl(myIdx, i1 & 63);
                int s2 = __shfl(myIdx, i2 & 63);
                int s3 = __shfl(myIdx, i3 & 63);
                if (i0 < n) {
                    float4 v = *(const float4*)(xin + (size_t)s0 * DD + gl * 4);
                    ax0 += v.x; ay0 += v.y; az0 += v.z; aw0 += v.w;
                }
                if (i1 < n) {
                    float4 v = *(const float4*)(xin + (size_t)s1 * DD + gl * 4);
                    ax1 += v.x; ay1 += v.y; az1 += v.z; aw1 += v.w;
                }
                if (i2 < n) {
                    float4 v = *(const float4*)(xin + (size_t)s2 * DD + gl * 4);
                    ax2 += v.x; ay2 += v.y; az2 += v.z; aw2 += v.w;
                }
                if (i3 < n) {
                    float4 v = *(const float4*)(xin + (size_t)s3 * DD + gl * 4);
                    ax3 += v.x; ay3 += v.y; az3 += v.z; aw3 += v.w;
                }
            }
        }
        float sx = (ax0 + ax1) + (ax2 + ax3);
        float sy = (ay0 + ay1) + (ay2 + ay3);
        float sz = (az0 + az1) + (az2 + az3);
        float sw = (aw0 + aw1) + (aw2 + aw3);
        sx += __shfl_xor(sx, 16); sy += __shfl_xor(sy, 16);
        sz += __shfl_xor(sz, 16); sw += __shfl_xor(sw, 16);
        sx += __shfl_xor(sx, 32); sy += __shfl_xor(sy, 32);
        sz += __shfl_xor(sz, 32); sw += __shfl_xor(sw, 32);
        if (g == 0) {
            float inv = 1.0f / (float)(deg > 0 ? deg : 1);
            float4 r; r.x = sx * inv; r.y = sy * inv; r.z = sz * inv; r.w = sw * inv;
            *(float4*)(aggr + (size_t)node * DD + gl * 4) = r;
        }
    }
}

// ---------- tri-dense v2: out = agg2@M1.T + agg1@M2.T + x@M3.T + bias ------
// THREAD = NODE. Each thread holds its own 64-float input row in VGPRs
// (16 independent float4 gathers, L1/L2-served); the weight operand M[f][k]
// has loop-uniform indices -> scalar (s_load) broadcasts on the scalar pipe.
// No LDS, no barriers, no wave-uniform vector loads. acc[FCH]+inreg[64]
// ~95 VGPR -> no spill, ~5 waves/SIMD. All array indices compile-time.
__global__ __launch_bounds__(256)
void tri_dense2(const float* __restrict__ agg2,
                const float* __restrict__ agg1,
                const float* __restrict__ x,
                const float* __restrict__ M1,
                const float* __restrict__ M2,
                const float* __restrict__ M3,
                const float* __restrict__ c0,
                const float* __restrict__ c1,
                const int* __restrict__ rs,
                float* __restrict__ out, int nN)
{
    int node = blockIdx.x * 256 + threadIdx.x;
    int gn = node < nN ? node : nN - 1;
    float ind = (rs[gn + 1] - rs[gn]) > 0 ? 1.0f : 0.0f;
    const size_t rowoff = (size_t)gn * DD;

#pragma unroll 1
    for (int fc = 0; fc < DD; fc += FCH) {
        float acc[FCH];
#pragma unroll
        for (int j = 0; j < FCH; ++j)
            acc[j] = fmaf(ind, c1[fc + j], c0[fc + j]);

#define PH(SRC, MM)                                                           \
        {                                                                     \
            float inreg[DD];                                                  \
            _Pragma("unroll")                                                 \
            for (int k = 0; k < DD; k += 4)                                   \
                *(float4*)&inreg[k] = *(const float4*)((SRC) + rowoff + k);   \
            _Pragma("unroll")                                                 \
            for (int j = 0; j < FCH; ++j) {                                   \
                const float* wr = (MM) + (fc + j) * DD;                       \
                float s0 = 0.f, s1 = 0.f;                                     \
                _Pragma("unroll")                                             \
                for (int k = 0; k < DD; k += 2) {                             \
                    s0 = fmaf(wr[k],     inreg[k],     s0);                   \
                    s1 = fmaf(wr[k + 1], inreg[k + 1], s1);                   \
                }                                                             \
                acc[j] += s0 + s1;                                            \
            }                                                                 \
        }
        PH(agg2, M1);
        PH(agg1, M2);
        PH(x,    M3);
#undef PH

        if (node < nN) {
#pragma unroll
            for (int v = 0; v < FCH; v += 4) {
                float4 o;
                o.x = acc[v]; o.y = acc[v + 1]; o.z = acc[v + 2]; o.w = acc[v + 3];
                *(float4*)(out + rowoff + fc + v) = o;
            }
        }
    }
}

extern "C" void kernel_launch(void* const* d_in, const int* in_sizes, int n_in,
                              void* d_out, int out_size, void* d_ws, size_t ws_size,
                              hipStream_t stream)
{
    const float* x   = (const float*)d_in[0];
    const int*   ei  = (const int*)d_in[1];
    const float* W1l = (const float*)d_in[2];
    const float* b1l = (const float*)d_in[3];
    const float* W1r = (const float*)d_in[4];
    const float* W2l = (const float*)d_in[5];
    const float* b2l = (const float*)d_in[6];
    const float* W2r = (const float*)d_in[7];
    float* out = (float*)d_out;

    int nN = in_sizes[0] / DD;   // 100000
    int nE = in_sizes[1] / 2;    // 1600000
    const int* src = ei;
    const int* dst = ei + nE;

    // ws layout (floats):
    // degi[nN] | rs[nN+1] | partials[128] | csr[nE] | pad-to-4 |
    // M1[4096] | M2[4096] | M3[4096] | c0[64] | c1[64] | agg1[nN*DD] | agg2[nN*DD]
    // rank[nE] aliases agg2 (dead before agg2 is born)
    int* degi     = (int*)d_ws;
    int* rs       = degi + nN;
    int* partials = rs + nN + 1;
    int* csr      = partials + 128;
    size_t ofs = (size_t)(nN + nN + 1 + 128 + nE);
    ofs = (ofs + 3) & ~(size_t)3;
    float* M1 = (float*)d_ws + ofs;
    float* M2 = M1 + DD * DD;
    float* M3 = M2 + DD * DD;
    float* c0 = M3 + DD * DD;
    float* c1 = c0 + DD;
    float* agg1 = c1 + DD;
    float* agg2 = agg1 + (size_t)nN * DD;
    int*   rank = (int*)agg2;

    int nblk = (nN + SCAN_T - 1) / SCAN_T;     // 98
    int nden = (nN + 255) / 256;               // 391

    // 1) histogram + rank
    hipMemsetAsync(degi, 0, sizeof(int) * (size_t)nN, stream);
    hist_kernel<<<2048, 256, 0, stream>>>(dst, degi, rank, nE);
    // 2) exclusive scan -> rs
    scan1_kernel<<<nblk, SCAN_T, 0, stream>>>(degi, rs, partials, nN);
    scan2_kernel<<<1, 64, 0, stream>>>(partials, rs, nblk, nN);
    scan3_kernel<<<nblk, SCAN_T, 0, stream>>>(rs, partials, nN);
    // 3) fill CSR (no atomics)
    fill_kernel<<<2048, 256, 0, stream>>>(src, dst, rs, rank, csr, nE);
    // 4) collapse weights
    prep_kernel<<<64, 64, 0, stream>>>(W1l, W1r, W2l, W2r, b1l, b2l,
                                       M1, M2, M3, c0, c1);
    // 5) two aggregations (rank alias now dead; agg2 may be written)
    aggregate_kernel<<<6144, 256, 0, stream>>>(x, csr, rs, agg1, nN);
    aggregate_kernel<<<6144, 256, 0, stream>>>(agg1, csr, rs, agg2, nN);
    // 6) single fused dense pass (LDS-free)
    tri_dense2<<<nden, 256, 0, stream>>>(agg2, agg1, x, M1, M2, M3,
                                         c0, c1, rs, out, nN);
}

// Round 11
// 381.531 us; speedup vs baseline: 1.8809x; 1.8809x over previous
//
#include <hip/hip_runtime.h>

#define DD 64
#define SCAN_T 1024
#define TILE_N 64

// ---------- CSR build ----------

// histogram + per-edge rank within its dst (rank = atomic return value)
__global__ __launch_bounds__(256)
void hist_kernel(const int* __restrict__ dst, int* __restrict__ degi,
                 int* __restrict__ rank, int nE)
{
    for (int e = blockIdx.x * blockDim.x + threadIdx.x; e < nE;
         e += gridDim.x * blockDim.x) {
        int r = atomicAdd(&degi[dst[e]], 1);
        rank[e] = r;
    }
}

__global__ __launch_bounds__(SCAN_T)
void scan1_kernel(const int* __restrict__ degi, int* __restrict__ rs,
                  int* __restrict__ partials, int nN)
{
    __shared__ int s[SCAN_T];
    int tid = threadIdx.x;
    int gid = blockIdx.x * SCAN_T + tid;
    int v = (gid < nN) ? degi[gid] : 0;
    s[tid] = v;
    __syncthreads();
    for (int off = 1; off < SCAN_T; off <<= 1) {
        int t = (tid >= off) ? s[tid - off] : 0;
        __syncthreads();
        s[tid] += t;
        __syncthreads();
    }
    if (gid < nN) rs[gid] = s[tid] - v;   // exclusive
    if (tid == SCAN_T - 1) partials[blockIdx.x] = s[SCAN_T - 1];
}

// wave-parallel exclusive scan over <=128 block partials
__global__ void scan2_kernel(int* __restrict__ partials, int* __restrict__ rs,
                             int nblk, int nN)
{
    int lane = threadIdx.x;   // 64 threads
    int p0 = (lane < nblk) ? partials[lane] : 0;
    int p1 = (64 + lane < nblk) ? partials[64 + lane] : 0;
    int v0 = p0;
    for (int off = 1; off < 64; off <<= 1) {
        int t = __shfl_up(v0, off);
        if (lane >= off) v0 += t;
    }
    int total0 = __shfl(v0, 63);
    int v1 = p1;
    for (int off = 1; off < 64; off <<= 1) {
        int t = __shfl_up(v1, off);
        if (lane >= off) v1 += t;
    }
    int grand = total0 + __shfl(v1, 63);
    if (lane < nblk) partials[lane] = v0 - p0;
    if (64 + lane < nblk) partials[64 + lane] = total0 + v1 - p1;
    if (lane == 0) rs[nN] = grand;   // == nE
}

__global__ __launch_bounds__(SCAN_T)
void scan3_kernel(int* __restrict__ rs, const int* __restrict__ partials, int nN)
{
    int gid = blockIdx.x * SCAN_T + threadIdx.x;
    if (gid < nN) rs[gid] += partials[blockIdx.x];
}

// scatter src into CSR slot rs[d]+rank[e] — NO atomics
__global__ __launch_bounds__(256)
void fill_kernel(const int* __restrict__ src, const int* __restrict__ dst,
                 const int* __restrict__ rs, const int* __restrict__ rank,
                 int* __restrict__ csr, int nE)
{
    for (int e = blockIdx.x * blockDim.x + threadIdx.x; e < nE;
         e += gridDim.x * blockDim.x) {
        csr[rs[dst[e]] + rank[e]] = src[e];
    }
}

// ---------- weight precompute: collapse the two layers ----------
// M1 = W2l*W1l ; M2 = W2l*W1r + W2r*W1l ; M3 = W2r*W1r
// c1 = b1 @ W2l.T ; c0 = b1 @ W2r.T + b2
// out = agg2@M1.T + agg1@M2.T + x@M3.T + ind*c1 + c0
__global__ void prep_kernel(const float* __restrict__ W1l,
                            const float* __restrict__ W1r,
                            const float* __restrict__ W2l,
                            const float* __restrict__ W2r,
                            const float* __restrict__ b1,
                            const float* __restrict__ b2,
                            float* __restrict__ M1, float* __restrict__ M2,
                            float* __restrict__ M3, float* __restrict__ c0,
                            float* __restrict__ c1)
{
    int f = blockIdx.x;      // 64 blocks
    int k = threadIdx.x;     // 64 threads
    float m1 = 0.f, m2 = 0.f, m3 = 0.f;
    for (int j = 0; j < DD; ++j) {
        float a2l = W2l[f * DD + j];
        float a2r = W2r[f * DD + j];
        float w1l = W1l[j * DD + k];
        float w1r = W1r[j * DD + k];
        m1 = fmaf(a2l, w1l, m1);
        m2 = fmaf(a2l, w1r, m2);
        m2 = fmaf(a2r, w1l, m2);
        m3 = fmaf(a2r, w1r, m3);
    }
    M1[f * DD + k] = m1;
    M2[f * DD + k] = m2;
    M3[f * DD + k] = m3;
    float t1 = W2l[f * DD + k] * b1[k];
    float t0 = W2r[f * DD + k] * b1[k];
    for (int off = 1; off < 64; off <<= 1) {
        t1 += __shfl_xor(t1, off);
        t0 += __shfl_xor(t0, off);
    }
    if (k == 0) {
        c1[f] = t1;
        c0[f] = t0 + b2[f];
    }
}

// ---------- aggregation: mean over neighbors ----------
// Wave per node. 16-lane group g handles neighbor rows {j+g, j+4+g, j+8+g,
// j+12+g}. BRANCH-FREE: always load (safe clamped index), kill out-of-range
// contributions with a 0/1 mask in the fma -> all 4 gathers issue
// back-to-back (no exec-mask serialization; R10 had VGPR=20 from guards).
__global__ __launch_bounds__(256, 6)
void aggregate_kernel(const float* __restrict__ xin,
                      const int* __restrict__ csr,
                      const int* __restrict__ rs,
                      float* __restrict__ aggr, int nN)
{
    int lane = threadIdx.x & 63;
    int w = threadIdx.x >> 6;
    int g  = lane >> 4;        // group 0..3
    int gl = lane & 15;        // lane within group
    int totWaves = gridDim.x * 4;
    for (int node = blockIdx.x * 4 + w; node < nN; node += totWaves) {
        int beg = rs[node], end = rs[node + 1];
        int deg = end - beg;
        float ax0 = 0.f, ay0 = 0.f, az0 = 0.f, aw0 = 0.f;
        float ax1 = 0.f, ay1 = 0.f, az1 = 0.f, aw1 = 0.f;
        float ax2 = 0.f, ay2 = 0.f, az2 = 0.f, aw2 = 0.f;
        float ax3 = 0.f, ay3 = 0.f, az3 = 0.f, aw3 = 0.f;
        for (int base = beg; base < end; base += 64) {
            int n = end - base;
            if (n > 64) n = 64;
            // lanes >= n carry index 0 (valid row) -> all shfl'd idx are safe
            int myIdx = (lane < n) ? csr[base + lane] : 0;
            for (int j = 0; j < n; j += 16) {
                int i0 = j + g;
                int i1 = j + 4 + g;
                int i2 = j + 8 + g;
                int i3 = j + 12 + g;
                int s0 = __shfl(myIdx, i0);
                int s1 = __shfl(myIdx, i1);
                int s2 = __shfl(myIdx, i2);
                int s3 = __shfl(myIdx, i3);
                float m0 = (i0 < n) ? 1.f : 0.f;
                float m1 = (i1 < n) ? 1.f : 0.f;
                float m2 = (i2 < n) ? 1.f : 0.f;
                float m3 = (i3 < n) ? 1.f : 0.f;
                float4 v0 = *(const float4*)(xin + (size_t)s0 * DD + gl * 4);
                float4 v1 = *(const float4*)(xin + (size_t)s1 * DD + gl * 4);
                float4 v2 = *(const float4*)(xin + (size_t)s2 * DD + gl * 4);
                float4 v3 = *(const float4*)(xin + (size_t)s3 * DD + gl * 4);
                ax0 = fmaf(m0, v0.x, ax0); ay0 = fmaf(m0, v0.y, ay0);
                az0 = fmaf(m0, v0.z, az0); aw0 = fmaf(m0, v0.w, aw0);
                ax1 = fmaf(m1, v1.x, ax1); ay1 = fmaf(m1, v1.y, ay1);
                az1 = fmaf(m1, v1.z, az1); aw1 = fmaf(m1, v1.w, aw1);
                ax2 = fmaf(m2, v2.x, ax2); ay2 = fmaf(m2, v2.y, ay2);
                az2 = fmaf(m2, v2.z, az2); aw2 = fmaf(m2, v2.w, aw2);
                ax3 = fmaf(m3, v3.x, ax3); ay3 = fmaf(m3, v3.y, ay3);
                az3 = fmaf(m3, v3.z, az3); aw3 = fmaf(m3, v3.w, aw3);
            }
        }
        float sx = (ax0 + ax1) + (ax2 + ax3);
        float sy = (ay0 + ay1) + (ay2 + ay3);
        float sz = (az0 + az1) + (az2 + az3);
        float sw = (aw0 + aw1) + (aw2 + aw3);
        sx += __shfl_xor(sx, 16); sy += __shfl_xor(sy, 16);
        sz += __shfl_xor(sz, 16); sw += __shfl_xor(sw, 16);
        sx += __shfl_xor(sx, 32); sy += __shfl_xor(sy, 32);
        sz += __shfl_xor(sz, 32); sw += __shfl_xor(sw, 32);
        if (g == 0) {
            float inv = 1.0f / (float)(deg > 0 ? deg : 1);
            float4 r; r.x = sx * inv; r.y = sy * inv; r.z = sz * inv; r.w = sw * inv;
            *(float4*)(aggr + (size_t)node * DD + gl * 4) = r;
        }
    }
}

// ---------- dense pass with bias: out = in @ W.T + c0 + ind*c1 ----------
// proven no-spill structure: one 64-float weight row per lane (~100 VGPR)
__global__ __launch_bounds__(256)
void dense_bias(const float* __restrict__ in,
                const float* __restrict__ W,
                const float* __restrict__ c0,
                const float* __restrict__ c1,
                const int* __restrict__ rs,
                float* __restrict__ out, int nN)
{
    __shared__ float t_lds[TILE_N * DD];
    int tid = threadIdx.x;
    int lane = tid & 63;
    int w = tid >> 6;

    float wreg[DD];
#pragma unroll
    for (int k = 0; k < DD; k += 4)
        *(float4*)&wreg[k] = *(const float4*)&W[lane * DD + k];
    float b0 = c0[lane];
    float b1v = c1[lane];

    int base = blockIdx.x * TILE_N;
#pragma unroll
    for (int i = 0; i < 4; ++i) {
        int flat = tid * 4 + i * 1024;
        int grow = base + (flat >> 6);
        if (grow >= nN) grow = nN - 1;
        *(float4*)&t_lds[flat] = *(const float4*)(in + (size_t)grow * DD + (flat & 63));
    }
    __syncthreads();

#pragma unroll 1
    for (int i = 0; i < 16; ++i) {
        int n = w * 16 + i;
        int gn = base + n;
        if (gn >= nN) break;
        const float* r = &t_lds[n * DD];
        float acc0 = 0.f, acc1 = 0.f;
#pragma unroll
        for (int k = 0; k < DD; k += 8) {
            float4 v0 = *(const float4*)(r + k);
            float4 v1 = *(const float4*)(r + k + 4);
            acc0 = fmaf(v0.x, wreg[k + 0], acc0);
            acc0 = fmaf(v0.y, wreg[k + 1], acc0);
            acc0 = fmaf(v0.z, wreg[k + 2], acc0);
            acc0 = fmaf(v0.w, wreg[k + 3], acc0);
            acc1 = fmaf(v1.x, wreg[k + 4], acc1);
            acc1 = fmaf(v1.y, wreg[k + 5], acc1);
            acc1 = fmaf(v1.z, wreg[k + 6], acc1);
            acc1 = fmaf(v1.w, wreg[k + 7], acc1);
        }
        float ind = (rs[gn + 1] - rs[gn]) > 0 ? 1.0f : 0.0f;
        out[(size_t)gn * DD + lane] = (acc0 + acc1) + fmaf(ind, b1v, b0);
    }
}

// ---------- dense accumulate pass: out += in @ W.T ----------
__global__ __launch_bounds__(256)
void dense_acc(const float* __restrict__ in,
               const float* __restrict__ W,
               float* __restrict__ out, int nN)
{
    __shared__ float t_lds[TILE_N * DD];
    int tid = threadIdx.x;
    int lane = tid & 63;
    int w = tid >> 6;

    float wreg[DD];
#pragma unroll
    for (int k = 0; k < DD; k += 4)
        *(float4*)&wreg[k] = *(const float4*)&W[lane * DD + k];

    int base = blockIdx.x * TILE_N;
#pragma unroll
    for (int i = 0; i < 4; ++i) {
        int flat = tid * 4 + i * 1024;
        int grow = base + (flat >> 6);
        if (grow >= nN) grow = nN - 1;
        *(float4*)&t_lds[flat] = *(const float4*)(in + (size_t)grow * DD + (flat & 63));
    }
    __syncthreads();

#pragma unroll 1
    for (int i = 0; i < 16; ++i) {
        int n = w * 16 + i;
        int gn = base + n;
        if (gn >= nN) break;
        const float* r = &t_lds[n * DD];
        float acc0 = 0.f, acc1 = 0.f;
#pragma unroll
        for (int k = 0; k < DD; k += 8) {
            float4 v0 = *(const float4*)(r + k);
            float4 v1 = *(const float4*)(r + k + 4);
            acc0 = fmaf(v0.x, wreg[k + 0], acc0);
            acc0 = fmaf(v0.y, wreg[k + 1], acc0);
            acc0 = fmaf(v0.z, wreg[k + 2], acc0);
            acc0 = fmaf(v0.w, wreg[k + 3], acc0);
            acc1 = fmaf(v1.x, wreg[k + 4], acc1);
            acc1 = fmaf(v1.y, wreg[k + 5], acc1);
            acc1 = fmaf(v1.z, wreg[k + 6], acc1);
            acc1 = fmaf(v1.w, wreg[k + 7], acc1);
        }
        size_t o = (size_t)gn * DD + lane;
        out[o] = out[o] + (acc0 + acc1);
    }
}

extern "C" void kernel_launch(void* const* d_in, const int* in_sizes, int n_in,
                              void* d_out, int out_size, void* d_ws, size_t ws_size,
                              hipStream_t stream)
{
    const float* x   = (const float*)d_in[0];
    const int*   ei  = (const int*)d_in[1];
    const float* W1l = (const float*)d_in[2];
    const float* b1l = (const float*)d_in[3];
    const float* W1r = (const float*)d_in[4];
    const float* W2l = (const float*)d_in[5];
    const float* b2l = (const float*)d_in[6];
    const float* W2r = (const float*)d_in[7];
    float* out = (float*)d_out;

    int nN = in_sizes[0] / DD;   // 100000
    int nE = in_sizes[1] / 2;    // 1600000
    const int* src = ei;
    const int* dst = ei + nE;

    // ws layout (floats):
    // degi[nN] | rs[nN+1] | partials[128] | csr[nE] | pad-to-4 |
    // M1[4096] | M2[4096] | M3[4096] | c0[64] | c1[64] | agg1[nN*DD] | agg2[nN*DD]
    // rank[nE] aliases agg2 (dead before agg2 is born)
    int* degi     = (int*)d_ws;
    int* rs       = degi + nN;
    int* partials = rs + nN + 1;
    int* csr      = partials + 128;
    size_t ofs = (size_t)(nN + nN + 1 + 128 + nE);
    ofs = (ofs + 3) & ~(size_t)3;
    float* M1 = (float*)d_ws + ofs;
    float* M2 = M1 + DD * DD;
    float* M3 = M2 + DD * DD;
    float* c0 = M3 + DD * DD;
    float* c1 = c0 + DD;
    float* agg1 = c1 + DD;
    float* agg2 = agg1 + (size_t)nN * DD;
    int*   rank = (int*)agg2;

    int nblk = (nN + SCAN_T - 1) / SCAN_T;   // 98
    int ntile = (nN + TILE_N - 1) / TILE_N;  // 1563

    // 1) histogram + rank
    hipMemsetAsync(degi, 0, sizeof(int) * (size_t)nN, stream);
    hist_kernel<<<2048, 256, 0, stream>>>(dst, degi, rank, nE);
    // 2) exclusive scan -> rs
    scan1_kernel<<<nblk, SCAN_T, 0, stream>>>(degi, rs, partials, nN);
    scan2_kernel<<<1, 64, 0, stream>>>(partials, rs, nblk, nN);
    scan3_kernel<<<nblk, SCAN_T, 0, stream>>>(rs, partials, nN);
    // 3) fill CSR (no atomics)
    fill_kernel<<<2048, 256, 0, stream>>>(src, dst, rs, rank, csr, nE);
    // 4) collapse weights
    prep_kernel<<<64, 64, 0, stream>>>(W1l, W1r, W2l, W2r, b1l, b2l,
                                       M1, M2, M3, c0, c1);
    // 5) two aggregations (rank alias now dead; agg2 may be written)
    aggregate_kernel<<<6144, 256, 0, stream>>>(x, csr, rs, agg1, nN);
    aggregate_kernel<<<6144, 256, 0, stream>>>(agg1, csr, rs, agg2, nN);
    // 6) three dense passes (R8-proven): out = agg2@M1.T + bias; += agg1@M2.T; += x@M3.T
    dense_bias<<<ntile, 256, 0, stream>>>(agg2, M1, c0, c1, rs, out, nN);
    dense_acc<<<ntile, 256, 0, stream>>>(agg1, M2, out, nN);
    dense_acc<<<ntile, 256, 0, stream>>>(x, M3, out, nN);
}

// Round 12
// 319.130 us; speedup vs baseline: 2.2487x; 1.1955x over previous
//
#include <hip/hip_runtime.h>

#define DD 64
#define SCAN_T 1024
#define DTILE 128

// ---------- CSR build ----------

// histogram + per-edge rank within its dst (rank = atomic return value)
__global__ __launch_bounds__(256)
void hist_kernel(const int* __restrict__ dst, int* __restrict__ degi,
                 int* __restrict__ rank, int nE)
{
    for (int e = blockIdx.x * blockDim.x + threadIdx.x; e < nE;
         e += gridDim.x * blockDim.x) {
        int r = atomicAdd(&degi[dst[e]], 1);
        rank[e] = r;
    }
}

__global__ __launch_bounds__(SCAN_T)
void scan1_kernel(const int* __restrict__ degi, int* __restrict__ rs,
                  int* __restrict__ partials, int nN)
{
    __shared__ int s[SCAN_T];
    int tid = threadIdx.x;
    int gid = blockIdx.x * SCAN_T + tid;
    int v = (gid < nN) ? degi[gid] : 0;
    s[tid] = v;
    __syncthreads();
    for (int off = 1; off < SCAN_T; off <<= 1) {
        int t = (tid >= off) ? s[tid - off] : 0;
        __syncthreads();
        s[tid] += t;
        __syncthreads();
    }
    if (gid < nN) rs[gid] = s[tid] - v;   // exclusive
    if (tid == SCAN_T - 1) partials[blockIdx.x] = s[SCAN_T - 1];
}

// wave-parallel exclusive scan over <=128 block partials
__global__ void scan2_kernel(int* __restrict__ partials, int* __restrict__ rs,
                             int nblk, int nN)
{
    int lane = threadIdx.x;   // 64 threads
    int p0 = (lane < nblk) ? partials[lane] : 0;
    int p1 = (64 + lane < nblk) ? partials[64 + lane] : 0;
    int v0 = p0;
    for (int off = 1; off < 64; off <<= 1) {
        int t = __shfl_up(v0, off);
        if (lane >= off) v0 += t;
    }
    int total0 = __shfl(v0, 63);
    int v1 = p1;
    for (int off = 1; off < 64; off <<= 1) {
        int t = __shfl_up(v1, off);
        if (lane >= off) v1 += t;
    }
    int grand = total0 + __shfl(v1, 63);
    if (lane < nblk) partials[lane] = v0 - p0;
    if (64 + lane < nblk) partials[64 + lane] = total0 + v1 - p1;
    if (lane == 0) rs[nN] = grand;   // == nE
}

__global__ __launch_bounds__(SCAN_T)
void scan3_kernel(int* __restrict__ rs, const int* __restrict__ partials, int nN)
{
    int gid = blockIdx.x * SCAN_T + threadIdx.x;
    if (gid < nN) rs[gid] += partials[blockIdx.x];
}

// scatter src into CSR slot rs[d]+rank[e] — NO atomics
__global__ __launch_bounds__(256)
void fill_kernel(const int* __restrict__ src, const int* __restrict__ dst,
                 const int* __restrict__ rs, const int* __restrict__ rank,
                 int* __restrict__ csr, int nE)
{
    for (int e = blockIdx.x * blockDim.x + threadIdx.x; e < nE;
         e += gridDim.x * blockDim.x) {
        csr[rs[dst[e]] + rank[e]] = src[e];
    }
}

// ---------- weight precompute: collapse the two layers ----------
// MT1 = (W2l*W1l)^T ; MT2 = (W2l*W1r + W2r*W1l)^T ; MT3 = (W2r*W1r)^T
// stored TRANSPOSED: MT[k*DD+f] so the dense kernel's per-k scalar row
// loads are contiguous (s_load_dwordx16).
// c1 = b1 @ W2l.T ; c0 = b1 @ W2r.T + b2
// out = agg2@M1.T + agg1@M2.T + x@M3.T + ind*c1 + c0
__global__ void prep_kernel(const float* __restrict__ W1l,
                            const float* __restrict__ W1r,
                            const float* __restrict__ W2l,
                            const float* __restrict__ W2r,
                            const float* __restrict__ b1,
                            const float* __restrict__ b2,
                            float* __restrict__ MT1, float* __restrict__ MT2,
                            float* __restrict__ MT3, float* __restrict__ c0,
                            float* __restrict__ c1)
{
    int f = blockIdx.x;      // 64 blocks
    int k = threadIdx.x;     // 64 threads
    float m1 = 0.f, m2 = 0.f, m3 = 0.f;
    for (int j = 0; j < DD; ++j) {
        float a2l = W2l[f * DD + j];
        float a2r = W2r[f * DD + j];
        float w1l = W1l[j * DD + k];
        float w1r = W1r[j * DD + k];
        m1 = fmaf(a2l, w1l, m1);
        m2 = fmaf(a2l, w1r, m2);
        m2 = fmaf(a2r, w1l, m2);
        m3 = fmaf(a2r, w1r, m3);
    }
    MT1[k * DD + f] = m1;
    MT2[k * DD + f] = m2;
    MT3[k * DD + f] = m3;
    float t1 = W2l[f * DD + k] * b1[k];
    float t0 = W2r[f * DD + k] * b1[k];
    for (int off = 1; off < 64; off <<= 1) {
        t1 += __shfl_xor(t1, off);
        t0 += __shfl_xor(t0, off);
    }
    if (k == 0) {
        c1[f] = t1;
        c0[f] = t0 + b2[f];
    }
}

// ---------- aggregation: mean over neighbors ----------
// Wave per node; 16-lane group g takes rows {j+g, j+4+g, ..., j+28+g}:
// EIGHT independent float4 gathers in flight per step (latency x MLP bound
// per R11 counters; 4-deep gave 3.5 TB/s, 8-deep targets ~5).
// Branch-free: masked slots gather a hot (L1-resident) line.
__global__ __launch_bounds__(256, 4)
void aggregate_kernel(const float* __restrict__ xin,
                      const int* __restrict__ csr,
                      const int* __restrict__ rs,
                      float* __restrict__ aggr, int nN)
{
    int lane = threadIdx.x & 63;
    int w = threadIdx.x >> 6;
    int g  = lane >> 4;        // group 0..3
    int gl = lane & 15;        // lane within group
    int totWaves = gridDim.x * 4;
    for (int node = blockIdx.x * 4 + w; node < nN; node += totWaves) {
        int beg = rs[node], end = rs[node + 1];
        int deg = end - beg;
        float4 a0 = {0,0,0,0}, a1 = {0,0,0,0}, a2 = {0,0,0,0}, a3 = {0,0,0,0};
        float4 a4 = {0,0,0,0}, a5 = {0,0,0,0}, a6 = {0,0,0,0}, a7 = {0,0,0,0};
        for (int base = beg; base < end; base += 64) {
            int n = end - base;
            if (n > 64) n = 64;
            // lanes >= n read csr[base] (valid, hot) so shfl'd idx are safe
            int myIdx = csr[(lane < n) ? (base + lane) : base];
            for (int j = 0; j < n; j += 32) {
#define GSLOT(S, ACC, OFS)                                                    \
                {                                                             \
                    int ii = j + (OFS) + g;                                   \
                    int si = __shfl(myIdx, ii & 63);                          \
                    float mm = (ii < n) ? 1.f : 0.f;                          \
                    float4 v = *(const float4*)(xin + (size_t)si * DD + gl * 4);\
                    ACC.x = fmaf(mm, v.x, ACC.x);                             \
                    ACC.y = fmaf(mm, v.y, ACC.y);                             \
                    ACC.z = fmaf(mm, v.z, ACC.z);                             \
                    ACC.w = fmaf(mm, v.w, ACC.w);                             \
                }
                GSLOT(0, a0, 0)  GSLOT(1, a1, 4)  GSLOT(2, a2, 8)  GSLOT(3, a3, 12)
                GSLOT(4, a4, 16) GSLOT(5, a5, 20) GSLOT(6, a6, 24) GSLOT(7, a7, 28)
#undef GSLOT
            }
        }
        float sx = ((a0.x + a1.x) + (a2.x + a3.x)) + ((a4.x + a5.x) + (a6.x + a7.x));
        float sy = ((a0.y + a1.y) + (a2.y + a3.y)) + ((a4.y + a5.y) + (a6.y + a7.y));
        float sz = ((a0.z + a1.z) + (a2.z + a3.z)) + ((a4.z + a5.z) + (a6.z + a7.z));
        float sw = ((a0.w + a1.w) + (a2.w + a3.w)) + ((a4.w + a5.w) + (a6.w + a7.w));
        sx += __shfl_xor(sx, 16); sy += __shfl_xor(sy, 16);
        sz += __shfl_xor(sz, 16); sw += __shfl_xor(sw, 16);
        sx += __shfl_xor(sx, 32); sy += __shfl_xor(sy, 32);
        sz += __shfl_xor(sz, 32); sw += __shfl_xor(sw, 32);
        if (g == 0) {
            float inv = 1.0f / (float)(deg > 0 ? deg : 1);
            float4 r; r.x = sx * inv; r.y = sy * inv; r.z = sz * inv; r.w = sw * inv;
            *(float4*)(aggr + (size_t)node * DD + gl * 4) = r;
        }
    }
}

// ---------- tri-dense v4: out = agg2@M1.T + agg1@M2.T + x@M3.T + bias ------
// THREAD = NODE, but rows staged through a stride-65 LDS tile:
//  - global reads: coalesced float4 staging (wave covers 1KB contiguous)
//  - LDS reads: lane-distinct own-row b32, bank (tid+k)%32 -> conflict-free
//  - weights MT[k][f]: loop-uniform indices -> scalar s_load (contiguous row)
// k-outer / f-unrolled: acc[64] static-indexed, ~600B inner body, ~75 VGPR.
__global__ __launch_bounds__(DTILE)
void tri_dense4(const float* __restrict__ agg2,
                const float* __restrict__ agg1,
                const float* __restrict__ x,
                const float* __restrict__ MT1,
                const float* __restrict__ MT2,
                const float* __restrict__ MT3,
                const float* __restrict__ c0,
                const float* __restrict__ c1,
                const int* __restrict__ rs,
                float* __restrict__ out, int nN)
{
    __shared__ float t_lds[DTILE * 65];
    int tid = threadIdx.x;
    int base = blockIdx.x * DTILE;
    int node = base + tid;
    int gn = node < nN ? node : nN - 1;

    float acc[DD];
    float ind = (rs[gn + 1] - rs[gn]) > 0 ? 1.0f : 0.0f;
#pragma unroll
    for (int f = 0; f < DD; ++f)
        acc[f] = fmaf(ind, c1[f], c0[f]);

#define STAGE(SRC)                                                            \
    {                                                                         \
        _Pragma("unroll")                                                     \
        for (int i = 0; i < 16; ++i) {                                        \
            int fi = i * DTILE + tid;                                         \
            int row = fi >> 4;                                                \
            int col = (fi & 15) * 4;                                          \
            int grow = base + row;                                            \
            if (grow >= nN) grow = nN - 1;                                    \
            *(float4*)&t_lds[row * 65 + col] =                                \
                *(const float4*)((SRC) + (size_t)grow * DD + col);            \
        }                                                                     \
    }

#define PHASE(MT)                                                             \
    {                                                                         \
        _Pragma("unroll 1")                                                   \
        for (int k = 0; k < DD; ++k) {                                        \
            float ink = t_lds[tid * 65 + k];                                  \
            const float* mrow = (MT) + k * DD;                                \
            _Pragma("unroll")                                                 \
            for (int f = 0; f < DD; ++f)                                      \
                acc[f] = fmaf(ink, mrow[f], acc[f]);                          \
        }                                                                     \
    }

    STAGE(agg2);
    __syncthreads();
    PHASE(MT1);
    __syncthreads();
    STAGE(agg1);
    __syncthreads();
    PHASE(MT2);
    __syncthreads();
    STAGE(x);
    __syncthreads();
    PHASE(MT3);

    if (node < nN) {
#pragma unroll
        for (int v = 0; v < DD; v += 4) {
            float4 o;
            o.x = acc[v]; o.y = acc[v + 1]; o.z = acc[v + 2]; o.w = acc[v + 3];
            *(float4*)(out + (size_t)node * DD + v) = o;
        }
    }
#undef STAGE
#undef PHASE
}

extern "C" void kernel_launch(void* const* d_in, const int* in_sizes, int n_in,
                              void* d_out, int out_size, void* d_ws, size_t ws_size,
                              hipStream_t stream)
{
    const float* x   = (const float*)d_in[0];
    const int*   ei  = (const int*)d_in[1];
    const float* W1l = (const float*)d_in[2];
    const float* b1l = (const float*)d_in[3];
    const float* W1r = (const float*)d_in[4];
    const float* W2l = (const float*)d_in[5];
    const float* b2l = (const float*)d_in[6];
    const float* W2r = (const float*)d_in[7];
    float* out = (float*)d_out;

    int nN = in_sizes[0] / DD;   // 100000
    int nE = in_sizes[1] / 2;    // 1600000
    const int* src = ei;
    const int* dst = ei + nE;

    // ws layout (floats):
    // degi[nN] | rs[nN+1] | partials[128] | csr[nE] | pad-to-4 |
    // MT1[4096] | MT2[4096] | MT3[4096] | c0[64] | c1[64] | agg1[nN*DD] | agg2[nN*DD]
    // rank[nE] aliases agg2 (dead before agg2 is born)
    int* degi     = (int*)d_ws;
    int* rs       = degi + nN;
    int* partials = rs + nN + 1;
    int* csr      = partials + 128;
    size_t ofs = (size_t)(nN + nN + 1 + 128 + nE);
    ofs = (ofs + 3) & ~(size_t)3;
    float* MT1 = (float*)d_ws + ofs;
    float* MT2 = MT1 + DD * DD;
    float* MT3 = MT2 + DD * DD;
    float* c0 = MT3 + DD * DD;
    float* c1 = c0 + DD;
    float* agg1 = c1 + DD;
    float* agg2 = agg1 + (size_t)nN * DD;
    int*   rank = (int*)agg2;

    int nblk = (nN + SCAN_T - 1) / SCAN_T;     // 98
    int nden = (nN + DTILE - 1) / DTILE;       // 782

    // 1) histogram + rank
    hipMemsetAsync(degi, 0, sizeof(int) * (size_t)nN, stream);
    hist_kernel<<<2048, 256, 0, stream>>>(dst, degi, rank, nE);
    // 2) exclusive scan -> rs
    scan1_kernel<<<nblk, SCAN_T, 0, stream>>>(degi, rs, partials, nN);
    scan2_kernel<<<1, 64, 0, stream>>>(partials, rs, nblk, nN);
    scan3_kernel<<<nblk, SCAN_T, 0, stream>>>(rs, partials, nN);
    // 3) fill CSR (no atomics)
    fill_kernel<<<2048, 256, 0, stream>>>(src, dst, rs, rank, csr, nE);
    // 4) collapse weights (transposed MT for scalar row loads)
    prep_kernel<<<64, 64, 0, stream>>>(W1l, W1r, W2l, W2r, b1l, b2l,
                                       MT1, MT2, MT3, c0, c1);
    // 5) two aggregations (rank alias now dead; agg2 may be written)
    aggregate_kernel<<<6144, 256, 0, stream>>>(x, csr, rs, agg1, nN);
    aggregate_kernel<<<6144, 256, 0, stream>>>(agg1, csr, rs, agg2, nN);
    // 6) single fused dense pass (thread=node, LDS-staged, scalar weights)
    tri_dense4<<<nden, DTILE, 0, stream>>>(agg2, agg1, x, MT1, MT2, MT3,
                                           c0, c1, rs, out, nN);
}